// Round 2
// baseline (1768.516 us; speedup 1.0000x reference)
//
#include <hip/hip_runtime.h>

#define H96 96
#define LAYERS 6
#define BN_EPS 1e-5f
#define SCAN_B 1024

typedef unsigned short u16;
typedef unsigned int u32;
typedef _Float16 f16;
typedef _Float16 h8 __attribute__((ext_vector_type(8)));
typedef float f32x4 __attribute__((ext_vector_type(4)));

__device__ __forceinline__ float sigm(float x) { return 1.f / (1.f + __expf(-x)); }
__device__ __forceinline__ float tanh_(float x) { return 2.f / (1.f + __expf(-2.f * x)) - 1.f; }
__device__ __forceinline__ f32x4 splat4(float x) { f32x4 v = {x, x, x, x}; return v; }

struct h2s { f16 x, y; };

// ---------- weight f32 -> f16 conversion (all GEMM weights, one launch) ----------
__global__ void k_f2h(const float* __restrict__ convw, const float* __restrict__ wih,
                      const float* __restrict__ whh, const float* __restrict__ fc1w,
                      const float* __restrict__ fc2w, f16* __restrict__ dst) {
    int i = blockIdx.x * 256 + threadIdx.x;
    if (i >= 184320) return;
    float v;
    if (i < 55296) v = convw[i];
    else if (i < 82944) v = wih[i - 55296];
    else if (i < 110592) v = whh[i - 82944];
    else if (i < 147456) v = fc1w[i - 110592];
    else v = fc2w[i - 147456];
    dst[i] = (f16)v;
}

// ---------- pad: h0 = pad(x, [N,32]->[N,96]) ----------
__global__ void k_pad(const float* __restrict__ x, float* __restrict__ hf32, f16* __restrict__ hf, int N) {
    int i = blockIdx.x * 256 + threadIdx.x;
    if (i >= N * H96) return;
    int n = i / H96, c = i - n * H96;
    float v = (c < 32) ? x[n * 32 + c] : 0.f;
    hf32[i] = v;
    hf[i] = (f16)v;
}

// ---------- CSR build ----------
__global__ void k_hist(const int* __restrict__ dst, int* __restrict__ deg, int E) {
    int e = blockIdx.x * 256 + threadIdx.x;
    if (e < E) atomicAdd(&deg[dst[e]], 1);
}

__global__ __launch_bounds__(SCAN_B) void k_scan1(const int* __restrict__ deg, int* __restrict__ incl,
                                                  int* __restrict__ bsum, int N) {
    __shared__ int sh[SCAN_B];
    int i = blockIdx.x * SCAN_B + threadIdx.x;
    int v = (i < N) ? deg[i] : 0;
    sh[threadIdx.x] = v;
    __syncthreads();
    for (int off = 1; off < SCAN_B; off <<= 1) {
        int t = (threadIdx.x >= (u32)off) ? sh[threadIdx.x - off] : 0;
        __syncthreads();
        sh[threadIdx.x] += t;
        __syncthreads();
    }
    incl[blockIdx.x * SCAN_B + threadIdx.x] = sh[threadIdx.x];
    if (threadIdx.x == SCAN_B - 1) bsum[blockIdx.x] = sh[threadIdx.x];
}

__global__ void k_scan2(int* __restrict__ bsum, int nb) {
    if (blockIdx.x == 0 && threadIdx.x == 0) {
        int run = 0;
        for (int i = 0; i < nb; i++) { run += bsum[i]; bsum[i] = run; }
    }
}

__global__ void k_scan3(const int* __restrict__ deg, const int* __restrict__ incl, const int* __restrict__ bsum,
                        int* __restrict__ rs, int* __restrict__ cur, int N, int E) {
    int i = blockIdx.x * 256 + threadIdx.x;
    if (i == 0) rs[N] = E;
    if (i < N) {
        int b = i / SCAN_B;
        int off = (b > 0) ? bsum[b - 1] : 0;
        int ex = incl[i] - deg[i] + off;
        rs[i] = ex;
        cur[i] = ex;
    }
}

__global__ void k_fill(const int* __restrict__ src, const int* __restrict__ dst, int* __restrict__ cur,
                       int* __restrict__ es, int E) {
    int e = blockIdx.x * 256 + threadIdx.x;
    if (e < E) {
        int p = atomicAdd(&cur[dst[e]], 1);
        es[p] = src[e];
    }
}

// ---------- conv GEMM: m = h @ W  (W row-major [96,96], transpose via LDS) ----------
__global__ __launch_bounds__(256) void k_conv(const f16* __restrict__ hf, const f16* __restrict__ W,
                                              f16* __restrict__ mout, int N) {
    __shared__ __align__(16) f16 WT[H96 * H96];  // WT[n*96+k] = W[k*96+n]
    int tid = threadIdx.x;
    for (int i = tid; i < H96 * H96; i += 256) {
        int k = i / H96, n = i - k * H96;
        WT[n * H96 + k] = W[i];
    }
    __syncthreads();
    int lane = tid & 63, wave = tid >> 6;
    int l15 = lane & 15, q = lane >> 4;
    h8 bfr[6][3];
#pragma unroll
    for (int t = 0; t < 6; t++)
#pragma unroll
        for (int s = 0; s < 3; s++)
            bfr[t][s] = *(const h8*)&WT[(t * 16 + l15) * H96 + s * 32 + q * 8];
    int ntiles = (N + 63) >> 6;
    for (int tile = blockIdx.x; tile < ntiles; tile += gridDim.x) {
        int rowa = tile * 64 + wave * 16 + l15;
        if (rowa >= N) rowa = N - 1;
        h8 af[3];
#pragma unroll
        for (int s = 0; s < 3; s++) af[s] = *(const h8*)(hf + (size_t)rowa * H96 + s * 32 + q * 8);
        f32x4 acc[6];
#pragma unroll
        for (int t = 0; t < 6; t++) acc[t] = splat4(0.f);
#pragma unroll
        for (int s = 0; s < 3; s++)
#pragma unroll
            for (int t = 0; t < 6; t++)
                acc[t] = __builtin_amdgcn_mfma_f32_16x16x32_f16(af[s], bfr[t][s], acc[t], 0, 0, 0);
        int rbase = tile * 64 + wave * 16 + q * 4;
#pragma unroll
        for (int rr = 0; rr < 4; rr++) {
            int row = rbase + rr;
            if (row >= N) continue;
            f16* dp = mout + (size_t)row * H96 + l15;
#pragma unroll
            for (int t = 0; t < 6; t++) dp[t * 16] = (f16)acc[t][rr];
        }
    }
}

// ---------- gather: agg[n] = sum_{e in in(n)} m[src_e]  (wave per node) ----------
__global__ __launch_bounds__(256) void k_gather(const f16* __restrict__ m, const int* __restrict__ rs,
                                                const int* __restrict__ es, f16* __restrict__ agg, int N) {
    int node = blockIdx.x * 4 + (threadIdx.x >> 6);
    int lane = threadIdx.x & 63;
    if (node >= N || lane >= 48) return;
    int s = rs[node], e = rs[node + 1];
    float ax = 0.f, ay = 0.f;
    for (int i = s; i < e; i++) {
        int sr = es[i];
        h2s v = *(const h2s*)(m + (size_t)sr * H96 + lane * 2);
        ax += (float)v.x;
        ay += (float)v.y;
    }
    h2s pk;
    pk.x = (f16)ax;
    pk.y = (f16)ay;
    *(h2s*)(agg + (size_t)node * H96 + lane * 2) = pk;
}

// ---------- fused GRU: gates from agg & h, state update ----------
__global__ __launch_bounds__(256) void k_gru(const f16* __restrict__ agg, f16* hf, float* hf32,
                                             const f16* __restrict__ wih, const f16* __restrict__ whh,
                                             const float* __restrict__ bih, const float* __restrict__ bhh, int N) {
    int lane = threadIdx.x & 63, wave = threadIdx.x >> 6;
    int l15 = lane & 15, q = lane >> 4;
    float b_r[6], b_z[6], b_in[6], b_hn[6];
#pragma unroll
    for (int t = 0; t < 6; t++) {
        int j = t * 16 + l15;
        b_r[t] = bih[j] + bhh[j];
        b_z[t] = bih[96 + j] + bhh[96 + j];
        b_in[t] = bih[192 + j];
        b_hn[t] = bhh[192 + j];
    }
    int ntiles = (N + 63) >> 6;
    for (int tile = blockIdx.x; tile < ntiles; tile += gridDim.x) {
        int rowa = tile * 64 + wave * 16 + l15;
        if (rowa >= N) rowa = N - 1;
        h8 aagg[3], ah[3];
#pragma unroll
        for (int s = 0; s < 3; s++) {
            aagg[s] = *(const h8*)(agg + (size_t)rowa * H96 + s * 32 + q * 8);
            ah[s] = *(const h8*)(hf + (size_t)rowa * H96 + s * 32 + q * 8);
        }
        f32x4 r[6], z[6], nn[6], hn[6];
#pragma unroll
        for (int t = 0; t < 6; t++) {
            r[t] = splat4(b_r[t]);
            z[t] = splat4(b_z[t]);
            nn[t] = splat4(b_in[t]);
            hn[t] = splat4(b_hn[t]);
        }
#pragma unroll
        for (int s = 0; s < 3; s++) {
#pragma unroll
            for (int t = 0; t < 6; t++) {
                int jr = t * 16 + l15;
                int ko = s * 32 + q * 8;
                h8 w0 = *(const h8*)(wih + (size_t)jr * H96 + ko);
                h8 w1 = *(const h8*)(whh + (size_t)jr * H96 + ko);
                r[t] = __builtin_amdgcn_mfma_f32_16x16x32_f16(aagg[s], w0, r[t], 0, 0, 0);
                r[t] = __builtin_amdgcn_mfma_f32_16x16x32_f16(ah[s], w1, r[t], 0, 0, 0);
                h8 w2 = *(const h8*)(wih + (size_t)(96 + jr) * H96 + ko);
                h8 w3 = *(const h8*)(whh + (size_t)(96 + jr) * H96 + ko);
                z[t] = __builtin_amdgcn_mfma_f32_16x16x32_f16(aagg[s], w2, z[t], 0, 0, 0);
                z[t] = __builtin_amdgcn_mfma_f32_16x16x32_f16(ah[s], w3, z[t], 0, 0, 0);
                h8 w4 = *(const h8*)(wih + (size_t)(192 + jr) * H96 + ko);
                h8 w5 = *(const h8*)(whh + (size_t)(192 + jr) * H96 + ko);
                nn[t] = __builtin_amdgcn_mfma_f32_16x16x32_f16(aagg[s], w4, nn[t], 0, 0, 0);
                hn[t] = __builtin_amdgcn_mfma_f32_16x16x32_f16(ah[s], w5, hn[t], 0, 0, 0);
            }
        }
        int rbase = tile * 64 + wave * 16 + q * 4;
#pragma unroll
        for (int t = 0; t < 6; t++) {
            int col = t * 16 + l15;
#pragma unroll
            for (int rr = 0; rr < 4; rr++) {
                int row = rbase + rr;
                if (row >= N) continue;
                float rv = sigm(r[t][rr]);
                float zv = sigm(z[t][rr]);
                float nv = tanh_(nn[t][rr] + rv * hn[t][rr]);
                size_t idx = (size_t)row * H96 + col;
                float hold = hf32[idx];
                float hnew = (1.f - zv) * nv + zv * hold;
                hf32[idx] = hnew;
                hf[idx] = (f16)hnew;
            }
        }
    }
}

// ---------- pool: sums[g] += relu(h[n]), counts[g] += 1 ----------
__global__ void k_pool(const float* __restrict__ hf32, const int* __restrict__ batch, float* __restrict__ sums,
                       int* __restrict__ counts, int N) {
    int idx = blockIdx.x * 256 + threadIdx.x;
    int node = idx / 48, c = idx - node * 48;
    if (node >= N) return;
    int g = batch[node];
    const float* p = hf32 + (size_t)node * H96 + c * 2;
    float vx = fmaxf(p[0], 0.f), vy = fmaxf(p[1], 0.f);
    atomicAdd(&sums[g * H96 + c * 2], vx);
    atomicAdd(&sums[g * H96 + c * 2 + 1], vy);
    if (c == 0) atomicAdd(&counts[g], 1);
}

__global__ void k_bnpool(const float* __restrict__ sums, const int* __restrict__ counts,
                         const float* __restrict__ gamma, const float* __restrict__ beta,
                         f16* __restrict__ pooled, int Gn) {
    int i = blockIdx.x * 256 + threadIdx.x;
    if (i >= Gn * H96) return;
    int g = i / H96, j = i - g * H96;
    float cnt = fmaxf((float)counts[g], 1.f);
    float mean = sums[i] / cnt;
    float val = mean * (gamma[j] * rsqrtf(1.f + BN_EPS)) + beta[j];
    pooled[i] = (f16)val;
}

// ---------- MLP GEMM: out = act(A @ W^T + b), W f16 row-major [NT*16, KS*32] ----------
template <int KS, int NT, bool RELU>
__global__ __launch_bounds__(256) void k_mlp(const f16* __restrict__ A, const f16* __restrict__ W,
                                             const float* __restrict__ bias, f16* __restrict__ out, int M) {
    int lane = threadIdx.x & 63, wave = threadIdx.x >> 6;
    int l15 = lane & 15, q = lane >> 4;
    int tile = blockIdx.x;
    int rowa = tile * 64 + wave * 16 + l15;
    if (rowa >= M) rowa = M - 1;
    h8 af[KS];
#pragma unroll
    for (int s = 0; s < KS; s++) af[s] = *(const h8*)(A + (size_t)rowa * (KS * 32) + s * 32 + q * 8);
    f32x4 acc[NT];
#pragma unroll
    for (int t = 0; t < NT; t++) acc[t] = splat4(0.f);
#pragma unroll
    for (int s = 0; s < KS; s++)
#pragma unroll
        for (int t = 0; t < NT; t++) {
            h8 b = *(const h8*)(W + (size_t)(t * 16 + l15) * (KS * 32) + s * 32 + q * 8);
            acc[t] = __builtin_amdgcn_mfma_f32_16x16x32_f16(af[s], b, acc[t], 0, 0, 0);
        }
    int rbase = tile * 64 + wave * 16 + q * 4;
#pragma unroll
    for (int t = 0; t < NT; t++) {
        float bv = bias[t * 16 + l15];
#pragma unroll
        for (int rr = 0; rr < 4; rr++) {
            int row = rbase + rr;
            if (row >= M) continue;
            float v = acc[t][rr] + bv;
            if (RELU) v = fmaxf(v, 0.f);
            out[(size_t)row * (NT * 16) + t * 16 + l15] = (f16)v;
        }
    }
}

__global__ void k_mlp3(const f16* __restrict__ h2, const float* __restrict__ w, const float* __restrict__ b,
                       float* __restrict__ out, int M) {
    int g = blockIdx.x * 256 + threadIdx.x;
    if (g >= M) return;
    float acc = 0.f;
    for (int k = 0; k < H96; k++) acc += (float)h2[(size_t)g * H96 + k] * w[k];
    out[g] = acc + b[0];
}

extern "C" void kernel_launch(void* const* d_in, const int* in_sizes, int n_in, void* d_out, int out_size,
                              void* d_ws, size_t ws_size, hipStream_t stream) {
    const float* x = (const float*)d_in[0];
    const int* ei = (const int*)d_in[1];
    const int* batch = (const int*)d_in[2];
    const float* conv_w = (const float*)d_in[3];
    const float* wih = (const float*)d_in[4];
    const float* whh = (const float*)d_in[5];
    const float* bih = (const float*)d_in[6];
    const float* bhh = (const float*)d_in[7];
    const float* gamma = (const float*)d_in[8];
    const float* beta = (const float*)d_in[9];
    const float* fc1w = (const float*)d_in[10];
    const float* fc1b = (const float*)d_in[11];
    const float* fc2w = (const float*)d_in[12];
    const float* fc2b = (const float*)d_in[13];
    const float* fc3w = (const float*)d_in[14];
    const float* fc3b = (const float*)d_in[15];

    int N = in_sizes[0] / 32;
    int E = in_sizes[1] / 2;
    int Gn = out_size;  // 4096
    const int* srcp = ei;
    const int* dstp = ei + E;

    char* p = (char*)d_ws;
    auto alloc = [&](size_t bytes) -> char* {
        char* r = p;
        p += (bytes + 255) & ~(size_t)255;
        return r;
    };
    float* hf32 = (float*)alloc((size_t)N * H96 * 4);
    f16* hf = (f16*)alloc((size_t)N * H96 * 2);
    f16* mf = (f16*)alloc((size_t)N * H96 * 2);
    f16* aggf = (f16*)alloc((size_t)N * H96 * 2);
    f16* wf16 = (f16*)alloc((size_t)184320 * 2);
    int nb = (N + SCAN_B - 1) / SCAN_B;
    int* deg = (int*)alloc((size_t)N * 4);
    int* incl = (int*)alloc((size_t)nb * SCAN_B * 4);
    int* bsum = (int*)alloc((size_t)nb * 4);
    int* rs = (int*)alloc((size_t)(N + 1) * 4);
    int* cur = (int*)alloc((size_t)N * 4);
    int* es = (int*)alloc((size_t)E * 4);
    float* sums = (float*)alloc((size_t)Gn * H96 * 4);
    int* counts = (int*)alloc((size_t)Gn * 4);
    f16* pooled = (f16*)alloc((size_t)Gn * H96 * 2);
    f16* h1 = (f16*)alloc((size_t)Gn * 384 * 2);
    f16* h2 = (f16*)alloc((size_t)Gn * H96 * 2);

    f16* convw16 = wf16;
    f16* wih16 = wf16 + 55296;
    f16* whh16 = wf16 + 82944;
    f16* fc1w16 = wf16 + 110592;
    f16* fc2w16 = wf16 + 147456;

    hipMemsetAsync(deg, 0, (size_t)N * 4, stream);
    hipMemsetAsync(sums, 0, (size_t)Gn * H96 * 4, stream);
    hipMemsetAsync(counts, 0, (size_t)Gn * 4, stream);

    k_f2h<<<720, 256, 0, stream>>>(conv_w, wih, whh, fc1w, fc2w, wf16);
    k_pad<<<(N * H96 + 255) / 256, 256, 0, stream>>>(x, hf32, hf, N);
    k_hist<<<(E + 255) / 256, 256, 0, stream>>>(dstp, deg, E);
    k_scan1<<<nb, SCAN_B, 0, stream>>>(deg, incl, bsum, N);
    k_scan2<<<1, 64, 0, stream>>>(bsum, nb);
    k_scan3<<<(N + 255) / 256, 256, 0, stream>>>(deg, incl, bsum, rs, cur, N, E);
    k_fill<<<(E + 255) / 256, 256, 0, stream>>>(srcp, dstp, cur, es, E);

    for (int l = 0; l < LAYERS; l++) {
        k_conv<<<512, 256, 0, stream>>>(hf, convw16 + (size_t)l * H96 * H96, mf, N);
        k_gather<<<(N + 3) / 4, 256, 0, stream>>>(mf, rs, es, aggf, N);
        k_gru<<<512, 256, 0, stream>>>(aggf, hf, hf32, wih16, whh16, bih, bhh, N);
    }

    k_pool<<<(N * 48 + 255) / 256, 256, 0, stream>>>(hf32, batch, sums, counts, N);
    k_bnpool<<<(Gn * H96 + 255) / 256, 256, 0, stream>>>(sums, counts, gamma, beta, pooled, Gn);
    k_mlp<3, 24, true><<<(Gn + 63) / 64, 256, 0, stream>>>(pooled, fc1w16, fc1b, h1, Gn);
    k_mlp<12, 6, true><<<(Gn + 63) / 64, 256, 0, stream>>>(h1, fc2w16, fc2b, h2, Gn);
    k_mlp3<<<(Gn + 255) / 256, 256, 0, stream>>>(h2, fc3w, fc3b, (float*)d_out, Gn);
}

// Round 3
// 826.805 us; speedup vs baseline: 2.1390x; 2.1390x over previous
//
#include <hip/hip_runtime.h>

#define H96 96
#define LAYERS 6
#define BN_EPS 1e-5f
#define SCAN_B 1024

typedef unsigned short u16;
typedef unsigned int u32;
typedef _Float16 f16;
typedef _Float16 h8 __attribute__((ext_vector_type(8)));
typedef float f32x4 __attribute__((ext_vector_type(4)));

__device__ __forceinline__ float sigm(float x) { return 1.f / (1.f + __expf(-x)); }
__device__ __forceinline__ float tanh_(float x) { return 2.f / (1.f + __expf(-2.f * x)) - 1.f; }
__device__ __forceinline__ f32x4 splat4(float x) { f32x4 v = {x, x, x, x}; return v; }

struct h2s { f16 x, y; };

// ---------- weight f32 -> f16 conversion (all GEMM weights, one launch) ----------
__global__ void k_f2h(const float* __restrict__ convw, const float* __restrict__ wih,
                      const float* __restrict__ whh, const float* __restrict__ fc1w,
                      const float* __restrict__ fc2w, f16* __restrict__ dst) {
    int i = blockIdx.x * 256 + threadIdx.x;
    if (i >= 184320) return;
    float v;
    if (i < 55296) v = convw[i];
    else if (i < 82944) v = wih[i - 55296];
    else if (i < 110592) v = whh[i - 82944];
    else if (i < 147456) v = fc1w[i - 110592];
    else v = fc2w[i - 147456];
    dst[i] = (f16)v;
}

// ---------- pad: h0 = pad(x, [N,32]->[N,96]) ----------
__global__ void k_pad(const float* __restrict__ x, float* __restrict__ hf32, f16* __restrict__ hf, int N) {
    int i = blockIdx.x * 256 + threadIdx.x;
    if (i >= N * H96) return;
    int n = i / H96, c = i - n * H96;
    float v = (c < 32) ? x[n * 32 + c] : 0.f;
    hf32[i] = v;
    hf[i] = (f16)v;
}

// ---------- CSR build (used for edge->dst CSR and for graph->node CSR) ----------
__global__ void k_hist(const int* __restrict__ key, int* __restrict__ deg, int E) {
    int e = blockIdx.x * 256 + threadIdx.x;
    if (e < E) atomicAdd(&deg[key[e]], 1);
}

__global__ __launch_bounds__(SCAN_B) void k_scan1(const int* __restrict__ deg, int* __restrict__ incl,
                                                  int* __restrict__ bsum, int N) {
    __shared__ int sh[SCAN_B];
    int i = blockIdx.x * SCAN_B + threadIdx.x;
    int v = (i < N) ? deg[i] : 0;
    sh[threadIdx.x] = v;
    __syncthreads();
    for (int off = 1; off < SCAN_B; off <<= 1) {
        int t = (threadIdx.x >= (u32)off) ? sh[threadIdx.x - off] : 0;
        __syncthreads();
        sh[threadIdx.x] += t;
        __syncthreads();
    }
    incl[blockIdx.x * SCAN_B + threadIdx.x] = sh[threadIdx.x];
    if (threadIdx.x == SCAN_B - 1) bsum[blockIdx.x] = sh[threadIdx.x];
}

__global__ void k_scan2(int* __restrict__ bsum, int nb) {
    if (blockIdx.x == 0 && threadIdx.x == 0) {
        int run = 0;
        for (int i = 0; i < nb; i++) { run += bsum[i]; bsum[i] = run; }
    }
}

__global__ void k_scan3(const int* __restrict__ deg, const int* __restrict__ incl, const int* __restrict__ bsum,
                        int* __restrict__ rs, int* __restrict__ cur, int N, int E) {
    int i = blockIdx.x * 256 + threadIdx.x;
    if (i == 0) rs[N] = E;
    if (i < N) {
        int b = i / SCAN_B;
        int off = (b > 0) ? bsum[b - 1] : 0;
        int ex = incl[i] - deg[i] + off;
        rs[i] = ex;
        if (cur) cur[i] = ex;
    }
}

__global__ void k_fill(const int* __restrict__ src, const int* __restrict__ dst, int* __restrict__ cur,
                       int* __restrict__ es, int E) {
    int e = blockIdx.x * 256 + threadIdx.x;
    if (e < E) {
        int p = atomicAdd(&cur[dst[e]], 1);
        es[p] = src[e];
    }
}

// ---------- conv GEMM: m = h @ W  (W f16 row-major [96,96], transpose via LDS) ----------
__global__ __launch_bounds__(256) void k_conv(const f16* __restrict__ hf, const f16* __restrict__ W,
                                              f16* __restrict__ mout, int N) {
    __shared__ __align__(16) f16 WT[H96 * H96];  // WT[n*96+k] = W[k*96+n]
    int tid = threadIdx.x;
    for (int i = tid; i < H96 * H96; i += 256) {
        int k = i / H96, n = i - k * H96;
        WT[n * H96 + k] = W[i];
    }
    __syncthreads();
    int lane = tid & 63, wave = tid >> 6;
    int l15 = lane & 15, q = lane >> 4;
    h8 bfr[6][3];
#pragma unroll
    for (int t = 0; t < 6; t++)
#pragma unroll
        for (int s = 0; s < 3; s++)
            bfr[t][s] = *(const h8*)&WT[(t * 16 + l15) * H96 + s * 32 + q * 8];
    int ntiles = (N + 63) >> 6;
    for (int tile = blockIdx.x; tile < ntiles; tile += gridDim.x) {
        int rowa = tile * 64 + wave * 16 + l15;
        if (rowa >= N) rowa = N - 1;
        h8 af[3];
#pragma unroll
        for (int s = 0; s < 3; s++) af[s] = *(const h8*)(hf + (size_t)rowa * H96 + s * 32 + q * 8);
        f32x4 acc[6];
#pragma unroll
        for (int t = 0; t < 6; t++) acc[t] = splat4(0.f);
#pragma unroll
        for (int s = 0; s < 3; s++)
#pragma unroll
            for (int t = 0; t < 6; t++)
                acc[t] = __builtin_amdgcn_mfma_f32_16x16x32_f16(af[s], bfr[t][s], acc[t], 0, 0, 0);
        int rbase = tile * 64 + wave * 16 + q * 4;
#pragma unroll
        for (int rr = 0; rr < 4; rr++) {
            int row = rbase + rr;
            if (row >= N) continue;
            f16* dp = mout + (size_t)row * H96 + l15;
#pragma unroll
            for (int t = 0; t < 6; t++) dp[t * 16] = (f16)acc[t][rr];
        }
    }
}

// ---------- gather: agg[n] = sum_{e in in(n)} m[src_e]  (wave per node, 4x unrolled) ----------
__global__ __launch_bounds__(256) void k_gather(const f16* __restrict__ m, const int* __restrict__ rs,
                                                const int* __restrict__ es, f16* __restrict__ agg, int N) {
    int node = blockIdx.x * 4 + (threadIdx.x >> 6);
    int lane = threadIdx.x & 63;
    if (node >= N || lane >= 48) return;
    int s = rs[node], e = rs[node + 1];
    float ax = 0.f, ay = 0.f;
    int i = s;
    for (; i + 4 <= e; i += 4) {
        int s0 = es[i], s1 = es[i + 1], s2 = es[i + 2], s3 = es[i + 3];
        u32 v0 = *(const u32*)(m + (size_t)s0 * H96 + lane * 2);
        u32 v1 = *(const u32*)(m + (size_t)s1 * H96 + lane * 2);
        u32 v2 = *(const u32*)(m + (size_t)s2 * H96 + lane * 2);
        u32 v3 = *(const u32*)(m + (size_t)s3 * H96 + lane * 2);
        h2s a = *(h2s*)&v0, b = *(h2s*)&v1, c = *(h2s*)&v2, d = *(h2s*)&v3;
        ax += (float)a.x + (float)b.x + (float)c.x + (float)d.x;
        ay += (float)a.y + (float)b.y + (float)c.y + (float)d.y;
    }
    for (; i < e; i++) {
        int sr = es[i];
        h2s v = *(const h2s*)(m + (size_t)sr * H96 + lane * 2);
        ax += (float)v.x;
        ay += (float)v.y;
    }
    h2s pk;
    pk.x = (f16)ax;
    pk.y = (f16)ay;
    *(h2s*)(agg + (size_t)node * H96 + lane * 2) = pk;
}

// ---------- fused GRU: 6 waves/block, wave t owns output cols [16t,16t+16) ----------
__global__ __launch_bounds__(384, 3) void k_gru(const f16* __restrict__ agg, f16* hf, float* hf32,
                                                const f16* __restrict__ wih, const f16* __restrict__ whh,
                                                const float* __restrict__ bih, const float* __restrict__ bhh,
                                                int N) {
    int t = threadIdx.x >> 6;  // 0..5
    int lane = threadIdx.x & 63;
    int l15 = lane & 15, q = lane >> 4;
    int jr = t * 16 + l15;
    float b_r = bih[jr] + bhh[jr];
    float b_z = bih[96 + jr] + bhh[96 + jr];
    float b_in = bih[192 + jr];
    float b_hn = bhh[192 + jr];
    h8 wr0[3], wr1[3], wz0[3], wz1[3], wn0[3], wn1[3];
#pragma unroll
    for (int s = 0; s < 3; s++) {
        int ko = s * 32 + q * 8;
        wr0[s] = *(const h8*)(wih + (size_t)jr * H96 + ko);
        wr1[s] = *(const h8*)(whh + (size_t)jr * H96 + ko);
        wz0[s] = *(const h8*)(wih + (size_t)(96 + jr) * H96 + ko);
        wz1[s] = *(const h8*)(whh + (size_t)(96 + jr) * H96 + ko);
        wn0[s] = *(const h8*)(wih + (size_t)(192 + jr) * H96 + ko);
        wn1[s] = *(const h8*)(whh + (size_t)(192 + jr) * H96 + ko);
    }
    int ntiles = (N + 15) >> 4;
    for (int tile = blockIdx.x; tile < ntiles; tile += gridDim.x) {
        int rowa = tile * 16 + l15;
        if (rowa >= N) rowa = N - 1;
        h8 aagg[3], ah[3];
#pragma unroll
        for (int s = 0; s < 3; s++) {
            aagg[s] = *(const h8*)(agg + (size_t)rowa * H96 + s * 32 + q * 8);
            ah[s] = *(const h8*)(hf + (size_t)rowa * H96 + s * 32 + q * 8);
        }
        f32x4 r = splat4(b_r), z = splat4(b_z), nn = splat4(b_in), hn = splat4(b_hn);
#pragma unroll
        for (int s = 0; s < 3; s++) {
            r = __builtin_amdgcn_mfma_f32_16x16x32_f16(aagg[s], wr0[s], r, 0, 0, 0);
            r = __builtin_amdgcn_mfma_f32_16x16x32_f16(ah[s], wr1[s], r, 0, 0, 0);
            z = __builtin_amdgcn_mfma_f32_16x16x32_f16(aagg[s], wz0[s], z, 0, 0, 0);
            z = __builtin_amdgcn_mfma_f32_16x16x32_f16(ah[s], wz1[s], z, 0, 0, 0);
            nn = __builtin_amdgcn_mfma_f32_16x16x32_f16(aagg[s], wn0[s], nn, 0, 0, 0);
            hn = __builtin_amdgcn_mfma_f32_16x16x32_f16(ah[s], wn1[s], hn, 0, 0, 0);
        }
        int rbase = tile * 16 + q * 4;
#pragma unroll
        for (int rr = 0; rr < 4; rr++) {
            int row = rbase + rr;
            if (row >= N) continue;
            float rv = sigm(r[rr]);
            float zv = sigm(z[rr]);
            float nv = tanh_(nn[rr] + rv * hn[rr]);
            size_t idx = (size_t)row * H96 + t * 16 + l15;
            float hold = hf32[idx];
            float hnew = (1.f - zv) * nv + zv * hold;
            hf32[idx] = hnew;
            hf[idx] = (f16)hnew;
        }
    }
}

// ---------- fused pool + BN: one block per graph (batch is sorted -> graph CSR) ----------
__global__ void k_pool2(const float* __restrict__ hf32, const int* __restrict__ grs,
                        const float* __restrict__ gamma, const float* __restrict__ beta,
                        f16* __restrict__ pooled, int Gn) {
    int g = blockIdx.x;
    int c = threadIdx.x;
    if (g >= Gn || c >= H96) return;
    int s = grs[g], e = grs[g + 1];
    float sum = 0.f;
    for (int n = s; n < e; n++) sum += fmaxf(hf32[(size_t)n * H96 + c], 0.f);
    float cnt = fmaxf((float)(e - s), 1.f);
    float val = (sum / cnt) * (gamma[c] * rsqrtf(1.f + BN_EPS)) + beta[c];
    pooled[(size_t)g * H96 + c] = (f16)val;
}

// ---------- MLP GEMM: out = act(A @ W^T + b), W f16 row-major [NT*16, KS*32] ----------
template <int KS, int NT, bool RELU>
__global__ __launch_bounds__(256) void k_mlp(const f16* __restrict__ A, const f16* __restrict__ W,
                                             const float* __restrict__ bias, f16* __restrict__ out, int M) {
    int lane = threadIdx.x & 63, wave = threadIdx.x >> 6;
    int l15 = lane & 15, q = lane >> 4;
    int tile = blockIdx.x;
    int rowa = tile * 64 + wave * 16 + l15;
    if (rowa >= M) rowa = M - 1;
    h8 af[KS];
#pragma unroll
    for (int s = 0; s < KS; s++) af[s] = *(const h8*)(A + (size_t)rowa * (KS * 32) + s * 32 + q * 8);
    f32x4 acc[NT];
#pragma unroll
    for (int t = 0; t < NT; t++) acc[t] = splat4(0.f);
#pragma unroll
    for (int s = 0; s < KS; s++)
#pragma unroll
        for (int t = 0; t < NT; t++) {
            h8 b = *(const h8*)(W + (size_t)(t * 16 + l15) * (KS * 32) + s * 32 + q * 8);
            acc[t] = __builtin_amdgcn_mfma_f32_16x16x32_f16(af[s], b, acc[t], 0, 0, 0);
        }
    int rbase = tile * 64 + wave * 16 + q * 4;
#pragma unroll
    for (int t = 0; t < NT; t++) {
        float bv = bias[t * 16 + l15];
#pragma unroll
        for (int rr = 0; rr < 4; rr++) {
            int row = rbase + rr;
            if (row >= M) continue;
            float v = acc[t][rr] + bv;
            if (RELU) v = fmaxf(v, 0.f);
            out[(size_t)row * (NT * 16) + t * 16 + l15] = (f16)v;
        }
    }
}

__global__ void k_mlp3(const f16* __restrict__ h2, const float* __restrict__ w, const float* __restrict__ b,
                       float* __restrict__ out, int M) {
    int g = blockIdx.x * 256 + threadIdx.x;
    if (g >= M) return;
    float acc = 0.f;
    for (int k = 0; k < H96; k++) acc += (float)h2[(size_t)g * H96 + k] * w[k];
    out[g] = acc + b[0];
}

extern "C" void kernel_launch(void* const* d_in, const int* in_sizes, int n_in, void* d_out, int out_size,
                              void* d_ws, size_t ws_size, hipStream_t stream) {
    const float* x = (const float*)d_in[0];
    const int* ei = (const int*)d_in[1];
    const int* batch = (const int*)d_in[2];
    const float* conv_w = (const float*)d_in[3];
    const float* wih = (const float*)d_in[4];
    const float* whh = (const float*)d_in[5];
    const float* bih = (const float*)d_in[6];
    const float* bhh = (const float*)d_in[7];
    const float* gamma = (const float*)d_in[8];
    const float* beta = (const float*)d_in[9];
    const float* fc1w = (const float*)d_in[10];
    const float* fc1b = (const float*)d_in[11];
    const float* fc2w = (const float*)d_in[12];
    const float* fc2b = (const float*)d_in[13];
    const float* fc3w = (const float*)d_in[14];
    const float* fc3b = (const float*)d_in[15];

    int N = in_sizes[0] / 32;
    int E = in_sizes[1] / 2;
    int Gn = out_size;  // 4096
    const int* srcp = ei;
    const int* dstp = ei + E;

    char* p = (char*)d_ws;
    auto alloc = [&](size_t bytes) -> char* {
        char* r = p;
        p += (bytes + 255) & ~(size_t)255;
        return r;
    };
    float* hf32 = (float*)alloc((size_t)N * H96 * 4);
    f16* hf = (f16*)alloc((size_t)N * H96 * 2);
    f16* mf = (f16*)alloc((size_t)N * H96 * 2);
    f16* aggf = (f16*)alloc((size_t)N * H96 * 2);
    f16* wf16 = (f16*)alloc((size_t)184320 * 2);
    int nb = (N + SCAN_B - 1) / SCAN_B;
    int* deg = (int*)alloc((size_t)N * 4);
    int* incl = (int*)alloc((size_t)nb * SCAN_B * 4);
    int* bsum = (int*)alloc((size_t)nb * 4);
    int* rs = (int*)alloc((size_t)(N + 1) * 4);
    int* cur = (int*)alloc((size_t)N * 4);
    int* es = (int*)alloc((size_t)E * 4);
    int nb2 = (Gn + SCAN_B - 1) / SCAN_B;
    int* gdeg = (int*)alloc((size_t)Gn * 4);
    int* gincl = (int*)alloc((size_t)nb2 * SCAN_B * 4);
    int* gbsum = (int*)alloc((size_t)nb2 * 4);
    int* grs = (int*)alloc((size_t)(Gn + 1) * 4);
    f16* pooled = (f16*)alloc((size_t)Gn * H96 * 2);
    f16* h1 = (f16*)alloc((size_t)Gn * 384 * 2);
    f16* h2 = (f16*)alloc((size_t)Gn * H96 * 2);

    f16* convw16 = wf16;
    f16* wih16 = wf16 + 55296;
    f16* whh16 = wf16 + 82944;
    f16* fc1w16 = wf16 + 110592;
    f16* fc2w16 = wf16 + 147456;

    hipMemsetAsync(deg, 0, (size_t)N * 4, stream);
    hipMemsetAsync(gdeg, 0, (size_t)Gn * 4, stream);

    k_f2h<<<720, 256, 0, stream>>>(conv_w, wih, whh, fc1w, fc2w, wf16);
    k_pad<<<(N * H96 + 255) / 256, 256, 0, stream>>>(x, hf32, hf, N);
    // edge CSR (by dst)
    k_hist<<<(E + 255) / 256, 256, 0, stream>>>(dstp, deg, E);
    k_scan1<<<nb, SCAN_B, 0, stream>>>(deg, incl, bsum, N);
    k_scan2<<<1, 64, 0, stream>>>(bsum, nb);
    k_scan3<<<(N + 255) / 256, 256, 0, stream>>>(deg, incl, bsum, rs, cur, N, E);
    k_fill<<<(E + 255) / 256, 256, 0, stream>>>(srcp, dstp, cur, es, E);
    // graph CSR (batch sorted)
    k_hist<<<(N + 255) / 256, 256, 0, stream>>>(batch, gdeg, N);
    k_scan1<<<nb2, SCAN_B, 0, stream>>>(gdeg, gincl, gbsum, Gn);
    k_scan2<<<1, 64, 0, stream>>>(gbsum, nb2);
    k_scan3<<<(Gn + 255) / 256, 256, 0, stream>>>(gdeg, gincl, gbsum, grs, (int*)nullptr, Gn, N);

    for (int l = 0; l < LAYERS; l++) {
        k_conv<<<512, 256, 0, stream>>>(hf, convw16 + (size_t)l * H96 * H96, mf, N);
        k_gather<<<(N + 3) / 4, 256, 0, stream>>>(mf, rs, es, aggf, N);
        k_gru<<<2048, 384, 0, stream>>>(aggf, hf, hf32, wih16, whh16, bih, bhh, N);
    }

    k_pool2<<<Gn, 128, 0, stream>>>(hf32, grs, gamma, beta, pooled, Gn);
    k_mlp<3, 24, true><<<(Gn + 63) / 64, 256, 0, stream>>>(pooled, fc1w16, fc1b, h1, Gn);
    k_mlp<12, 6, true><<<(Gn + 63) / 64, 256, 0, stream>>>(h1, fc2w16, fc2b, h2, Gn);
    k_mlp3<<<(Gn + 255) / 256, 256, 0, stream>>>(h2, fc3w, fc3b, (float*)d_out, Gn);
}